// Round 1
// baseline (475.452 us; speedup 1.0000x reference)
//
#include <hip/hip_runtime.h>

// Problem constants (fixed by reference setup_inputs)
constexpr int B = 16;
constexpr int C = 256;
constexpr int T = 16000;
constexpr int Q = T / 4;                   // float4 columns per (b,c) row = 4000
constexpr int SEG = 64;                    // t4-columns per block window (256 t scalars)
constexpr int NSEG = (Q + SEG - 1) / SEG;  // 63 windows per b
constexpr float EPS = 1e-8f;

typedef float f4 __attribute__((ext_vector_type(4)));

// ---------------------------------------------------------------------------
// K1: one block per (window, b). lane <-> t4 column (wave64 == 64 columns),
// wave w sums channels {w, w+4, ...} (64 chans each, coalesced 1KB/load).
// Cross-wave LDS reduce, then wave 0 does the in-window inclusive scan:
// fp32 within each float4 (4-element runs), DOUBLE carries across lanes.
// Writes per-t window-inclusive cumsums (2MB) + per-window totals (doubles).
// x loads are CACHED (not NT): x is 262MB vs 256MB L3 -> K2 re-read can hit.
// ---------------------------------------------------------------------------
__global__ __launch_bounds__(256) void sumscan_kernel(
    const float* __restrict__ x,
    float* __restrict__ scan_s,
    float* __restrict__ scan_p,
    double* __restrict__ tot_s,
    double* __restrict__ tot_p) {
  const int seg = blockIdx.x;
  const int b   = blockIdx.y;
  const int w   = threadIdx.x >> 6;
  const int l   = threadIdx.x & 63;
  const int t4  = seg * SEG + l;
  const bool act = t4 < Q;        // seg 62 covers only 32 columns

  f4 s = {0.f, 0.f, 0.f, 0.f};
  f4 p = {0.f, 0.f, 0.f, 0.f};
  if (act) {
    const f4* xb = reinterpret_cast<const f4*>(x + (size_t)b * C * T);
#pragma unroll 8
    for (int cc = 0; cc < C / 4; ++cc) {
      const int c = cc * 4 + w;
      f4 v = xb[(size_t)c * Q + t4];
      s += v;
      p += v * v;
    }
  }

  __shared__ f4 ls[4][64], lp[4][64];
  ls[w][l] = s;
  lp[w][l] = p;
  __syncthreads();

  if (w != 0) return;   // no further barriers; waves 1-3 done

  f4 cs = ls[0][l] + ls[1][l] + ls[2][l] + ls[3][l];
  f4 cp = lp[0][l] + lp[1][l] + lp[2][l] + lp[3][l];
  // inclusive scan within the lane's 4 t-values (short fp32 run)
  cs[1] += cs[0]; cs[2] += cs[1]; cs[3] += cs[2];
  cp[1] += cp[0]; cp[2] += cp[1]; cp[3] += cp[2];

  // wave-level inclusive scan of lane totals in double (wave 0 only; cheap)
  double rs = (double)cs[3], rp = (double)cp[3];
#pragma unroll
  for (int off = 1; off < 64; off <<= 1) {
    double ns = __shfl_up(rs, off);
    double np = __shfl_up(rp, off);
    if (l >= off) { rs += ns; rp += np; }
  }
  const double es = rs - (double)cs[3];   // exclusive prefix within window
  const double ep = rp - (double)cp[3];

  if (act) {
    f4 os, op;
#pragma unroll
    for (int i = 0; i < 4; ++i) {
      os[i] = (float)(es + (double)cs[i]);
      op[i] = (float)(ep + (double)cp[i]);
    }
    reinterpret_cast<f4*>(scan_s + (size_t)b * T)[t4] = os;
    reinterpret_cast<f4*>(scan_p + (size_t)b * T)[t4] = op;
  }
  if (l == 63) {   // window total (padding lanes contributed zeros)
    tot_s[b * NSEG + seg] = rs;
    tot_p[b * NSEG + seg] = rp;
  }
}

// ---------------------------------------------------------------------------
// K2: same block geometry. Each wave butterfly-reduces the <=62 preceding
// window totals (doubles, L2-hit) into the exclusive cross-window prefix,
// computes mean/istd for its 4 t-values in registers, then applies across
// 64 channels. x loads cached (L3-hit candidates from K1); out stores NT so
// the 262MB write stream doesn't evict x from L3.
// ---------------------------------------------------------------------------
__global__ __launch_bounds__(256) void apply_kernel(
    const float* __restrict__ x,
    const float* __restrict__ scan_s,
    const float* __restrict__ scan_p,
    const double* __restrict__ tot_s,
    const double* __restrict__ tot_p,
    const float* __restrict__ gain,
    const float* __restrict__ bias,
    float* __restrict__ out) {
  const int seg = blockIdx.x;
  const int b   = blockIdx.y;
  const int w   = threadIdx.x >> 6;
  const int l   = threadIdx.x & 63;
  const int t4  = seg * SEG + l;
  const bool act = t4 < Q;

  // exclusive prefix over windows [0, seg): lane l contributes tot[b][l] iff l < seg
  double vs = (l < seg) ? tot_s[b * NSEG + l] : 0.0;
  double vp = (l < seg) ? tot_p[b * NSEG + l] : 0.0;
#pragma unroll
  for (int off = 32; off > 0; off >>= 1) {
    vs += __shfl_xor(vs, off);
    vp += __shfl_xor(vp, off);
  }

  if (act) {
    const f4 cs = reinterpret_cast<const f4*>(scan_s + (size_t)b * T)[t4];
    const f4 cp = reinterpret_cast<const f4*>(scan_p + (size_t)b * T)[t4];
    f4 m, is;
#pragma unroll
    for (int i = 0; i < 4; ++i) {
      const int t = t4 * 4 + i;
      const float cnt  = (float)(t + 1) * (float)C;      // exact in fp32 (< 2^24)
      const float cums = (float)(vs + (double)cs[i]);
      const float cump = (float)(vp + (double)cp[i]);
      const float mean = cums / cnt;
      const float var  = cump / cnt - mean * mean;
      m[i]  = mean;
      is[i] = rsqrtf(var + EPS);
    }

    const f4* xb = reinterpret_cast<const f4*>(x   + (size_t)b * C * T);
    f4*       ob = reinterpret_cast<f4*>      (out + (size_t)b * C * T);
#pragma unroll 8
    for (int cc = 0; cc < C / 4; ++cc) {
      const int c = cc * 4 + w;        // wave-uniform -> scalar gain/bias loads
      const float g  = gain[c];
      const float bi = bias[c];
      f4 v = xb[(size_t)c * Q + t4];
      f4 o = (v - m) * is * g + bi;
      __builtin_nontemporal_store(o, &ob[(size_t)c * Q + t4]);
    }
  }
}

extern "C" void kernel_launch(void* const* d_in, const int* in_sizes, int n_in,
                              void* d_out, int out_size, void* d_ws, size_t ws_size,
                              hipStream_t stream) {
  const float* x    = (const float*)d_in[0];
  const float* gain = (const float*)d_in[1];
  const float* bias = (const float*)d_in[2];
  float* out = (float*)d_out;

  // ws: scan_s[B*T] f32 | scan_p[B*T] f32 | tot_s[B*NSEG] f64 | tot_p[B*NSEG] f64
  float*  scan_s = (float*)d_ws;
  float*  scan_p = scan_s + (size_t)B * T;
  double* tot_s  = (double*)(scan_p + (size_t)B * T);   // byte off 2,048,000: 8-aligned
  double* tot_p  = tot_s + (size_t)B * NSEG;

  dim3 grid(NSEG, B);   // 1008 blocks, 256 threads (4 waves)
  sumscan_kernel<<<grid, 256, 0, stream>>>(x, scan_s, scan_p, tot_s, tot_p);
  apply_kernel<<<grid, 256, 0, stream>>>(x, scan_s, scan_p, tot_s, tot_p,
                                         gain, bias, out);
}

// Round 2
// 471.719 us; speedup vs baseline: 1.0079x; 1.0079x over previous
//
#include <hip/hip_runtime.h>

// Problem constants (fixed by reference setup_inputs)
constexpr int B = 16;
constexpr int C = 256;
constexpr int T = 16000;
constexpr int Q = T / 4;                   // float4 columns per (b,c) row = 4000
constexpr int SEG = 64;                    // t4-columns per block window (256 t scalars)
constexpr int NSEG = (Q + SEG - 1) / SEG;  // 63 windows per b
constexpr float EPS = 1e-8f;

typedef float f4 __attribute__((ext_vector_type(4)));

// ---------------------------------------------------------------------------
// K1: one block per (window, b). lane <-> t4 column (wave64 == 64 columns),
// wave w sums channels {w, w+4, ...} (64 chans each, coalesced 1KB/load).
// Cross-wave LDS reduce, then wave 0 does the in-window inclusive scan:
// fp32 within each float4 (4-element runs), DOUBLE carries across lanes.
// Writes per-t window-inclusive cumsums (2MB) + per-window totals (doubles).
// x loads are CACHED (not NT): x is 262MB vs 256MB L3. K1 streams x in
// ASCENDING (b,seg) order, so at K1 completion L3 holds the LAST ~256MB of x
// (all but the first ~6MB). K2 exploits this by walking BACKWARD.
// ---------------------------------------------------------------------------
__global__ __launch_bounds__(256) void sumscan_kernel(
    const float* __restrict__ x,
    float* __restrict__ scan_s,
    float* __restrict__ scan_p,
    double* __restrict__ tot_s,
    double* __restrict__ tot_p) {
  const int seg = blockIdx.x;
  const int b   = blockIdx.y;
  const int w   = threadIdx.x >> 6;
  const int l   = threadIdx.x & 63;
  const int t4  = seg * SEG + l;
  const bool act = t4 < Q;        // seg 62 covers only 32 columns

  f4 s = {0.f, 0.f, 0.f, 0.f};
  f4 p = {0.f, 0.f, 0.f, 0.f};
  if (act) {
    const f4* xb = reinterpret_cast<const f4*>(x + (size_t)b * C * T);
#pragma unroll 8
    for (int cc = 0; cc < C / 4; ++cc) {
      const int c = cc * 4 + w;
      f4 v = xb[(size_t)c * Q + t4];
      s += v;
      p += v * v;
    }
  }

  __shared__ f4 ls[4][64], lp[4][64];
  ls[w][l] = s;
  lp[w][l] = p;
  __syncthreads();

  if (w != 0) return;   // no further barriers; waves 1-3 done

  f4 cs = ls[0][l] + ls[1][l] + ls[2][l] + ls[3][l];
  f4 cp = lp[0][l] + lp[1][l] + lp[2][l] + lp[3][l];
  // inclusive scan within the lane's 4 t-values (short fp32 run)
  cs[1] += cs[0]; cs[2] += cs[1]; cs[3] += cs[2];
  cp[1] += cp[0]; cp[2] += cp[1]; cp[3] += cp[2];

  // wave-level inclusive scan of lane totals in double (wave 0 only; cheap)
  double rs = (double)cs[3], rp = (double)cp[3];
#pragma unroll
  for (int off = 1; off < 64; off <<= 1) {
    double ns = __shfl_up(rs, off);
    double np = __shfl_up(rp, off);
    if (l >= off) { rs += ns; rp += np; }
  }
  const double es = rs - (double)cs[3];   // exclusive prefix within window
  const double ep = rp - (double)cp[3];

  if (act) {
    f4 os, op;
#pragma unroll
    for (int i = 0; i < 4; ++i) {
      os[i] = (float)(es + (double)cs[i]);
      op[i] = (float)(ep + (double)cp[i]);
    }
    reinterpret_cast<f4*>(scan_s + (size_t)b * T)[t4] = os;
    reinterpret_cast<f4*>(scan_p + (size_t)b * T)[t4] = op;
  }
  if (l == 63) {   // window total (padding lanes contributed zeros)
    tot_s[b * NSEG + seg] = rs;
    tot_p[b * NSEG + seg] = rp;
  }
}

// ---------------------------------------------------------------------------
// K2: REVERSED block order (seg' = NSEG-1-bx, b' = B-1-by). Earliest-dispatched
// blocks read the x lines K1 touched LAST -> L3-resident; hits don't evict,
// so the backward walk stays inside the resident set (~98% of x). out stores
// are nontemporal so the 262MB write stream doesn't allocate/evict in cache.
// Each wave butterfly-reduces the <=62 preceding window totals (doubles) into
// the exclusive cross-window prefix, computes mean/istd in registers, applies.
// ---------------------------------------------------------------------------
__global__ __launch_bounds__(256) void apply_kernel(
    const float* __restrict__ x,
    const float* __restrict__ scan_s,
    const float* __restrict__ scan_p,
    const double* __restrict__ tot_s,
    const double* __restrict__ tot_p,
    const float* __restrict__ gain,
    const float* __restrict__ bias,
    float* __restrict__ out) {
  const int seg = NSEG - 1 - blockIdx.x;   // reverse: L3-hot lines first
  const int b   = B - 1 - blockIdx.y;
  const int w   = threadIdx.x >> 6;
  const int l   = threadIdx.x & 63;
  const int t4  = seg * SEG + l;
  const bool act = t4 < Q;

  // exclusive prefix over windows [0, seg): lane l contributes tot[b][l] iff l < seg
  double vs = (l < seg) ? tot_s[b * NSEG + l] : 0.0;
  double vp = (l < seg) ? tot_p[b * NSEG + l] : 0.0;
#pragma unroll
  for (int off = 32; off > 0; off >>= 1) {
    vs += __shfl_xor(vs, off);
    vp += __shfl_xor(vp, off);
  }

  if (act) {
    const f4 cs = reinterpret_cast<const f4*>(scan_s + (size_t)b * T)[t4];
    const f4 cp = reinterpret_cast<const f4*>(scan_p + (size_t)b * T)[t4];
    f4 m, is;
#pragma unroll
    for (int i = 0; i < 4; ++i) {
      const int t = t4 * 4 + i;
      const float cnt  = (float)(t + 1) * (float)C;      // exact in fp32 (< 2^24)
      const float cums = (float)(vs + (double)cs[i]);
      const float cump = (float)(vp + (double)cp[i]);
      const float mean = cums / cnt;
      const float var  = cump / cnt - mean * mean;
      m[i]  = mean;
      is[i] = rsqrtf(var + EPS);
    }

    const f4* xb = reinterpret_cast<const f4*>(x   + (size_t)b * C * T);
    f4*       ob = reinterpret_cast<f4*>      (out + (size_t)b * C * T);
#pragma unroll 8
    for (int cc = 0; cc < C / 4; ++cc) {
      const int c = cc * 4 + w;        // wave-uniform -> scalar gain/bias loads
      const float g  = gain[c];
      const float bi = bias[c];
      f4 v = xb[(size_t)c * Q + t4];
      f4 o = (v - m) * is * g + bi;
      __builtin_nontemporal_store(o, &ob[(size_t)c * Q + t4]);
    }
  }
}

extern "C" void kernel_launch(void* const* d_in, const int* in_sizes, int n_in,
                              void* d_out, int out_size, void* d_ws, size_t ws_size,
                              hipStream_t stream) {
  const float* x    = (const float*)d_in[0];
  const float* gain = (const float*)d_in[1];
  const float* bias = (const float*)d_in[2];
  float* out = (float*)d_out;

  // ws: scan_s[B*T] f32 | scan_p[B*T] f32 | tot_s[B*NSEG] f64 | tot_p[B*NSEG] f64
  float*  scan_s = (float*)d_ws;
  float*  scan_p = scan_s + (size_t)B * T;
  double* tot_s  = (double*)(scan_p + (size_t)B * T);   // byte off 2,048,000: 8-aligned
  double* tot_p  = tot_s + (size_t)B * NSEG;

  dim3 grid(NSEG, B);   // 1008 blocks, 256 threads (4 waves)
  sumscan_kernel<<<grid, 256, 0, stream>>>(x, scan_s, scan_p, tot_s, tot_p);
  apply_kernel<<<grid, 256, 0, stream>>>(x, scan_s, scan_p, tot_s, tot_p,
                                         gain, bias, out);
}